// Round 1
// baseline (49708.771 us; speedup 1.0000x reference)
//
#include <hip/hip_runtime.h>
#include <math.h>

#define HH   1024
#define TT   64
#define NBAT 256
#define G3   3072   // 3*H
#define IN0  150
#define NCLS 60
#define ENC_W 2048  // 2*H

// ---------------- BatchNorm stats: one block per feature ----------------
__global__ void bigru_bn_stats(const float* __restrict__ x,
                               float* __restrict__ mean, float* __restrict__ istd) {
    int f = blockIdx.x;           // 0..149
    int tid = threadIdx.x;
    double s = 0.0, s2 = 0.0;
    for (int i = tid; i < NBAT * TT; i += blockDim.x) {
        float v = x[(size_t)i * IN0 + f];
        s += v; s2 += (double)v * v;
    }
    __shared__ double sh[256], sh2[256];
    sh[tid] = s; sh2[tid] = s2;
    __syncthreads();
    for (int off = 128; off > 0; off >>= 1) {
        if (tid < off) { sh[tid] += sh[tid + off]; sh2[tid] += sh2[tid + off]; }
        __syncthreads();
    }
    if (tid == 0) {
        double m = sh[0] / (NBAT * TT);
        double var = sh2[0] / (NBAT * TT) - m * m;
        mean[f] = (float)m;
        istd[f] = (float)(1.0 / sqrt(var + 1e-5));
    }
}

// ---------------- BatchNorm apply ----------------
__global__ void bigru_bn_apply(const float* __restrict__ x,
                               const float* __restrict__ mean, const float* __restrict__ istd,
                               const float* __restrict__ gamma, const float* __restrict__ beta,
                               float* __restrict__ xn) {
    int idx = blockIdx.x * blockDim.x + threadIdx.x;
    if (idx >= NBAT * TT * IN0) return;
    int f = idx % IN0;
    xn[idx] = (x[idx] - mean[f]) * istd[f] * gamma[f] + beta[f];
}

// ---------------- Per-step GEMM: computes gi (which=0) or gh (which=1) for dir d ----
// C[M=256, N=3072] = A[256,K] @ W[3072,K]^T + bias   (tiled 64x64, 4x4 per thread)
__global__ __launch_bounds__(256)
void bigru_step_gemm(const float* __restrict__ xslice, int lda_x, int Kx,
                     const float* __restrict__ w_ih, const float* __restrict__ b_ih,
                     float* __restrict__ gi,
                     const float* __restrict__ h,
                     const float* __restrict__ w_hh, const float* __restrict__ b_hh,
                     float* __restrict__ gh) {
    int d = blockIdx.z & 1;
    int which = blockIdx.z >> 1;

    const float* A; int lda, K;
    const float* W; const float* bias; float* C;
    if (which == 0) {
        A = xslice; lda = lda_x; K = Kx;
        W = w_ih + (size_t)d * G3 * Kx; bias = b_ih + d * G3;
        C = gi + (size_t)d * NBAT * G3;
    } else {
        A = h + (size_t)d * NBAT * HH; lda = HH; K = HH;
        W = w_hh + (size_t)d * G3 * HH; bias = b_hh + d * G3;
        C = gh + (size_t)d * NBAT * G3;
    }

    int row0 = blockIdx.y * 64;   // over M=256
    int col0 = blockIdx.x * 64;   // over N=3072

    __shared__ float As[16][64];
    __shared__ float Bs[16][64];

    int tid = threadIdx.x;
    int tx = tid & 15;      // col group
    int ty = tid >> 4;      // row group
    float acc[4][4] = {};

    for (int k0 = 0; k0 < K; k0 += 16) {
        #pragma unroll
        for (int i = 0; i < 4; ++i) {
            int e = tid * 4 + i;
            int m = e >> 4, k = e & 15;
            float v = 0.f;
            if (k0 + k < K) v = A[(size_t)(row0 + m) * lda + k0 + k];
            As[k][m] = v;
        }
        #pragma unroll
        for (int i = 0; i < 4; ++i) {
            int e = tid * 4 + i;
            int n = e >> 4, k = e & 15;
            float v = 0.f;
            if (k0 + k < K) v = W[(size_t)(col0 + n) * K + k0 + k];
            Bs[k][n] = v;
        }
        __syncthreads();
        #pragma unroll
        for (int kk = 0; kk < 16; ++kk) {
            float4 a = *(const float4*)&As[kk][ty * 4];
            float4 b = *(const float4*)&Bs[kk][tx * 4];
            acc[0][0] += a.x * b.x; acc[0][1] += a.x * b.y; acc[0][2] += a.x * b.z; acc[0][3] += a.x * b.w;
            acc[1][0] += a.y * b.x; acc[1][1] += a.y * b.y; acc[1][2] += a.y * b.z; acc[1][3] += a.y * b.w;
            acc[2][0] += a.z * b.x; acc[2][1] += a.z * b.y; acc[2][2] += a.z * b.z; acc[2][3] += a.z * b.w;
            acc[3][0] += a.w * b.x; acc[3][1] += a.w * b.y; acc[3][2] += a.w * b.z; acc[3][3] += a.w * b.w;
        }
        __syncthreads();
    }

    float4 bb = *(const float4*)&bias[col0 + tx * 4];
    #pragma unroll
    for (int i = 0; i < 4; ++i) {
        float4 o;
        o.x = acc[i][0] + bb.x; o.y = acc[i][1] + bb.y;
        o.z = acc[i][2] + bb.z; o.w = acc[i][3] + bb.w;
        *(float4*)&C[(size_t)(row0 + ty * 4 + i) * G3 + col0 + tx * 4] = o;
    }
}

// ---------------- Gate fusion + hidden update + output write ----------------
__global__ void bigru_gates(const float* __restrict__ gi, const float* __restrict__ gh,
                            float* __restrict__ h, float* __restrict__ enc, int t) {
    int idx = blockIdx.x * blockDim.x + threadIdx.x;   // 2*256*1024 total
    int d = idx >> 18;              // / (256*1024)
    int r = idx & ((NBAT * HH) - 1);
    int n = r >> 10;
    int j = r & (HH - 1);

    size_t base = (size_t)d * NBAT * G3 + (size_t)n * G3;
    float ir = gi[base + j];
    float iz = gi[base + HH + j];
    float in_ = gi[base + 2 * HH + j];
    float hr = gh[base + j];
    float hz = gh[base + HH + j];
    float hn = gh[base + 2 * HH + j];

    float rg = 1.f / (1.f + __expf(-(ir + hr)));
    float zg = 1.f / (1.f + __expf(-(iz + hz)));
    float ng = tanhf(in_ + rg * hn);

    size_t hidx = (size_t)d * NBAT * HH + (size_t)n * HH + j;
    float hprev = h[hidx];
    float hnew = (1.f - zg) * ng + zg * hprev;
    h[hidx] = hnew;
    enc[(size_t)n * TT * ENC_W + (size_t)t * ENC_W + d * HH + j] = hnew;
}

// ---------------- FC head: out[256,60] from enc[:, T-1, :] ----------------
__global__ void bigru_fc(const float* __restrict__ enc, const float* __restrict__ fc_w,
                         const float* __restrict__ fc_b, float* __restrict__ out) {
    int n = blockIdx.x;
    int tid = threadIdx.x;
    __shared__ float hbuf[ENC_W];
    for (int k = tid; k < ENC_W; k += blockDim.x)
        hbuf[k] = enc[(size_t)n * TT * ENC_W + (size_t)(TT - 1) * ENC_W + k];
    __syncthreads();
    if (tid < NCLS) {
        float acc = fc_b[tid];
        for (int k = 0; k < ENC_W; ++k)
            acc += hbuf[k] * fc_w[(size_t)tid * ENC_W + k];
        out[(size_t)n * NCLS + tid] = acc;
    }
}

extern "C" void kernel_launch(void* const* d_in, const int* in_sizes, int n_in,
                              void* d_out, int out_size, void* d_ws, size_t ws_size,
                              hipStream_t stream) {
    const float* x        = (const float*)d_in[0];
    const float* bn_gamma = (const float*)d_in[1];
    const float* bn_beta  = (const float*)d_in[2];
    const float* w_ih[3]  = {(const float*)d_in[3], (const float*)d_in[7],  (const float*)d_in[11]};
    const float* w_hh[3]  = {(const float*)d_in[4], (const float*)d_in[8],  (const float*)d_in[12]};
    const float* b_ih[3]  = {(const float*)d_in[5], (const float*)d_in[9],  (const float*)d_in[13]};
    const float* b_hh[3]  = {(const float*)d_in[6], (const float*)d_in[10], (const float*)d_in[14]};
    const float* fc_w     = (const float*)d_in[15];
    const float* fc_b     = (const float*)d_in[16];

    float* out = (float*)d_out;
    float* enc = out + NBAT * NCLS;           // [256, 64, 2048]

    float* ws   = (float*)d_ws;
    float* mean = ws;                          // 150 (pad to 256)
    float* istd = ws + 256;                    // 150 (pad to 256)
    float* xn   = ws + 512;                    // 16384*150
    float* gi   = xn + NBAT * TT * IN0;        // 2*256*3072
    float* gh   = gi + 2 * NBAT * G3;          // 2*256*3072
    float* h    = gh + 2 * NBAT * G3;          // 2*256*1024

    bigru_bn_stats<<<IN0, 256, 0, stream>>>(x, mean, istd);
    bigru_bn_apply<<<(NBAT * TT * IN0 + 255) / 256, 256, 0, stream>>>(
        x, mean, istd, bn_gamma, bn_beta, xn);

    for (int l = 0; l < 3; ++l) {
        hipMemsetAsync(h, 0, (size_t)2 * NBAT * HH * sizeof(float), stream);
        const float* in_base = (l == 0) ? xn : enc;
        int K_in  = (l == 0) ? IN0 : ENC_W;
        int lda   = TT * K_in;
        for (int t = 0; t < TT; ++t) {
            const float* xslice = in_base + (size_t)t * K_in;
            bigru_step_gemm<<<dim3(G3 / 64, NBAT / 64, 4), 256, 0, stream>>>(
                xslice, lda, K_in, w_ih[l], b_ih[l], gi, h, w_hh[l], b_hh[l], gh);
            bigru_gates<<<(2 * NBAT * HH) / 256, 256, 0, stream>>>(gi, gh, h, enc, t);
        }
    }

    bigru_fc<<<NBAT, 256, 0, stream>>>(enc, fc_w, fc_b, out);
}

// Round 2
// 7595.338 us; speedup vs baseline: 6.5446x; 6.5446x over previous
//
#include <hip/hip_runtime.h>
#include <hip/hip_bf16.h>
#include <math.h>

#define HH    1024
#define TT    64
#define NBAT  256
#define G3    3072
#define IN0   150
#define IN0P  160   // padded K for layer 0
#define NCLS  60
#define ENC_W 2048

typedef float  f32x4 __attribute__((ext_vector_type(4)));
typedef short  s16x8 __attribute__((ext_vector_type(8)));

#define GLOAD16(gsrc, ldst) \
  __builtin_amdgcn_global_load_lds((const __attribute__((address_space(1))) unsigned int*)(gsrc), \
                                   (__attribute__((address_space(3))) unsigned int*)(ldst), 16, 0, 0)

static __device__ inline short f2bf(float f) {
    __hip_bfloat16 h = __float2bfloat16(f);
    return *(short*)&h;
}

// ---------------- BatchNorm stats ----------------
__global__ void bigru_bn_stats(const float* __restrict__ x,
                               float* __restrict__ mean, float* __restrict__ istd) {
    int f = blockIdx.x;
    int tid = threadIdx.x;
    double s = 0.0, s2 = 0.0;
    for (int i = tid; i < NBAT * TT; i += blockDim.x) {
        float v = x[(size_t)i * IN0 + f];
        s += v; s2 += (double)v * v;
    }
    __shared__ double sh[256], sh2[256];
    sh[tid] = s; sh2[tid] = s2;
    __syncthreads();
    for (int off = 128; off > 0; off >>= 1) {
        if (tid < off) { sh[tid] += sh[tid + off]; sh2[tid] += sh2[tid + off]; }
        __syncthreads();
    }
    if (tid == 0) {
        double m = sh[0] / (NBAT * TT);
        double var = sh2[0] / (NBAT * TT) - m * m;
        mean[f] = (float)m;
        istd[f] = (float)(1.0 / sqrt(var + 1e-5));
    }
}

// ---------------- BN apply -> padded bf16 [16384][160] ----------------
__global__ void bigru_bn_apply_bf16(const float* __restrict__ x,
                                    const float* __restrict__ mean, const float* __restrict__ istd,
                                    const float* __restrict__ gamma, const float* __restrict__ beta,
                                    short* __restrict__ xn) {
    int idx = blockIdx.x * blockDim.x + threadIdx.x;
    if (idx >= NBAT * TT * IN0P) return;
    int f = idx % IN0P;
    int r = idx / IN0P;
    float v = 0.f;
    if (f < IN0) v = (x[(size_t)r * IN0 + f] - mean[f]) * istd[f] * gamma[f] + beta[f];
    xn[idx] = f2bf(v);
}

// ---------------- Convert w_ih_0 [2][3072][150] -> padded bf16 [2][3072][160] ----
__global__ void bigru_cvt_wih0(const float* __restrict__ src, short* __restrict__ dst) {
    int idx = blockIdx.x * blockDim.x + threadIdx.x;
    if (idx >= 2 * G3 * IN0P) return;
    int f = idx % IN0P;
    int r = idx / IN0P;
    float v = (f < IN0) ? src[(size_t)r * IN0 + f] : 0.f;
    dst[idx] = f2bf(v);
}

// ---------------- Generic f32 -> bf16 convert (n % 4 == 0) ----------------
__global__ void bigru_cvt4(const float* __restrict__ src, short* __restrict__ dst, int n4) {
    int i = blockIdx.x * blockDim.x + threadIdx.x;
    if (i >= n4) return;
    float4 v = ((const float4*)src)[i];
    short4 o;
    o.x = f2bf(v.x); o.y = f2bf(v.y); o.z = f2bf(v.z); o.w = f2bf(v.w);
    ((short4*)dst)[i] = o;
}

// ---------------- Bulk gi GEMM: C[2][Mchunk][3072] = A @ W^T + b_ih ----------------
// A rows map r -> (tt = r>>8, n = r&255) -> Abase + (n*64 + t0 + tt)*ldA
// 128x128 tile, BK=32, 4 waves of 64x64, mfma 16x16x32 bf16
__global__ __launch_bounds__(256)
void bigru_gi_gemm(const short* __restrict__ Abase, int ldA, int K,
                   const short* __restrict__ W,       // [2][3072][K]
                   const float* __restrict__ b_ih,    // [2][3072]
                   float* __restrict__ gi,            // [2][Mchunk][3072]
                   int t0, int Mchunk) {
    int d    = blockIdx.z;
    int col0 = blockIdx.x * 128;
    int row0 = blockIdx.y * 128;

    __shared__ short As[128][32];
    __shared__ short Bs[128][32];

    int tid  = threadIdx.x;
    int lane = tid & 63;
    int w    = tid >> 6;
    int wm   = w & 1, wn = w >> 1;

    f32x4 acc[4][4];
    #pragma unroll
    for (int i = 0; i < 4; ++i)
        #pragma unroll
        for (int j = 0; j < 4; ++j)
            acc[i][j] = (f32x4){0.f, 0.f, 0.f, 0.f};

    const short* Wd = W + (size_t)d * G3 * K;
    int sr = lane >> 2;
    int sc = (lane & 3) * 8;

    for (int k0 = 0; k0 < K; k0 += 32) {
        #pragma unroll
        for (int q = 0; q < 2; ++q) {
            int r  = w * 32 + q * 16 + sr;            // 0..127
            int gr = row0 + r;
            int tt = gr >> 8, n = gr & 255;
            const short* ga = Abase + (size_t)(n * TT + t0 + tt) * ldA + k0 + sc;
            GLOAD16(ga, &As[w * 32 + q * 16][0]);
            const short* gb = Wd + (size_t)(col0 + r) * K + k0 + sc;
            GLOAD16(gb, &Bs[w * 32 + q * 16][0]);
        }
        __syncthreads();

        int fr = lane & 15, fq = (lane >> 4) * 8;
        s16x8 a[4], b[4];
        #pragma unroll
        for (int i = 0; i < 4; ++i) a[i] = *(const s16x8*)&As[wm * 64 + i * 16 + fr][fq];
        #pragma unroll
        for (int j = 0; j < 4; ++j) b[j] = *(const s16x8*)&Bs[wn * 64 + j * 16 + fr][fq];
        #pragma unroll
        for (int i = 0; i < 4; ++i)
            #pragma unroll
            for (int j = 0; j < 4; ++j)
                acc[i][j] = __builtin_amdgcn_mfma_f32_16x16x32_bf16(a[i], b[j], acc[i][j], 0, 0, 0);
        __syncthreads();
    }

    int fr = lane & 15, quad = lane >> 4;
    #pragma unroll
    for (int j = 0; j < 4; ++j) {
        int c = col0 + wn * 64 + j * 16 + fr;
        float bias = b_ih[d * G3 + c];
        #pragma unroll
        for (int i = 0; i < 4; ++i) {
            #pragma unroll
            for (int reg = 0; reg < 4; ++reg) {
                int r = row0 + wm * 64 + i * 16 + quad * 4 + reg;
                gi[((size_t)d * Mchunk + r) * G3 + c] = acc[i][j][reg] + bias;
            }
        }
    }
}

// ---------------- Fused recurrence step: gh GEMM (64x64x3 gates) + gates ----------------
__global__ __launch_bounds__(256)
void bigru_step(const short* __restrict__ h_bf_in,   // [2][256][1024]
                short* __restrict__ h_bf_out,
                float* __restrict__ h,               // [2][256][1024] fp32 master
                const short* __restrict__ w_hh,      // [2][3072][1024] bf16
                const float* __restrict__ b_hh,      // [2][3072]
                const float* __restrict__ gi,        // [2][Mchunk][3072]
                int tt, int t, int Mchunk,
                float* __restrict__ enc,             // [256][64][2048]
                short* __restrict__ enc_bf) {        // may be null (layer 2)
    int j0 = blockIdx.x * 64;
    int m0 = blockIdx.y * 64;
    int d  = blockIdx.z;

    __shared__ short As[64][32];
    __shared__ short Bs[192][32];

    int tid  = threadIdx.x;
    int lane = tid & 63;
    int w    = tid >> 6;

    f32x4 acc[4][3];
    #pragma unroll
    for (int jj = 0; jj < 4; ++jj)
        #pragma unroll
        for (int g = 0; g < 3; ++g)
            acc[jj][g] = (f32x4){0.f, 0.f, 0.f, 0.f};

    const short* hb = h_bf_in + (size_t)d * NBAT * HH;
    const short* Wd = w_hh + (size_t)d * G3 * HH;
    int sr = lane >> 2;
    int sc = (lane & 3) * 8;

    for (int k0 = 0; k0 < HH; k0 += 32) {
        {   // A: 1 instr/wave, 16 rows each
            int r = w * 16 + sr;                      // 0..63
            const short* ga = hb + (size_t)(m0 + r) * HH + k0 + sc;
            GLOAD16(ga, &As[w * 16][0]);
        }
        #pragma unroll
        for (int q = 0; q < 3; ++q) {                 // B: 192 rows total
            int r = w * 48 + q * 16 + sr;             // 0..191
            int g = r >> 6, jl = r & 63;
            const short* gb = Wd + (size_t)(g * HH + j0 + jl) * HH + k0 + sc;
            GLOAD16(gb, &Bs[w * 48 + q * 16][0]);
        }
        __syncthreads();

        int fr = lane & 15, fq = (lane >> 4) * 8;
        s16x8 a = *(const s16x8*)&As[w * 16 + fr][fq];
        #pragma unroll
        for (int jj = 0; jj < 4; ++jj)
            #pragma unroll
            for (int g = 0; g < 3; ++g) {
                s16x8 b = *(const s16x8*)&Bs[g * 64 + jj * 16 + fr][fq];
                acc[jj][g] = __builtin_amdgcn_mfma_f32_16x16x32_bf16(a, b, acc[jj][g], 0, 0, 0);
            }
        __syncthreads();
    }

    int fr = lane & 15, quad = lane >> 4;
    #pragma unroll
    for (int jj = 0; jj < 4; ++jj) {
        int j = j0 + jj * 16 + fr;
        float bhr = b_hh[d * G3 + j];
        float bhz = b_hh[d * G3 + HH + j];
        float bhn = b_hh[d * G3 + 2 * HH + j];
        #pragma unroll
        for (int reg = 0; reg < 4; ++reg) {
            int n = m0 + w * 16 + quad * 4 + reg;
            size_t gib = ((size_t)d * Mchunk + tt * NBAT + n) * G3;
            float ir  = gi[gib + j];
            float iz  = gi[gib + HH + j];
            float inn = gi[gib + 2 * HH + j];
            float hr = acc[jj][0][reg] + bhr;
            float hz = acc[jj][1][reg] + bhz;
            float hn = acc[jj][2][reg] + bhn;
            float rg = 1.f / (1.f + __expf(-(ir + hr)));
            float zg = 1.f / (1.f + __expf(-(iz + hz)));
            float ng = tanhf(inn + rg * hn);
            size_t hidx = ((size_t)d * NBAT + n) * HH + j;
            float hprev = h[hidx];
            float hnew = (1.f - zg) * ng + zg * hprev;
            h[hidx] = hnew;
            h_bf_out[hidx] = f2bf(hnew);
            size_t eidx = ((size_t)n * TT + t) * ENC_W + d * HH + j;
            enc[eidx] = hnew;
            if (enc_bf) enc_bf[eidx] = f2bf(hnew);
        }
    }
}

// ---------------- FC head ----------------
__global__ void bigru_fc(const float* __restrict__ enc, const float* __restrict__ fc_w,
                         const float* __restrict__ fc_b, float* __restrict__ out) {
    int n = blockIdx.x;
    int tid = threadIdx.x;
    __shared__ float hbuf[ENC_W];
    for (int k = tid; k < ENC_W; k += blockDim.x)
        hbuf[k] = enc[(size_t)n * TT * ENC_W + (size_t)(TT - 1) * ENC_W + k];
    __syncthreads();
    if (tid < NCLS) {
        float acc = fc_b[tid];
        for (int k = 0; k < ENC_W; ++k)
            acc += hbuf[k] * fc_w[(size_t)tid * ENC_W + k];
        out[(size_t)n * NCLS + tid] = acc;
    }
}

extern "C" void kernel_launch(void* const* d_in, const int* in_sizes, int n_in,
                              void* d_out, int out_size, void* d_ws, size_t ws_size,
                              hipStream_t stream) {
    const float* x        = (const float*)d_in[0];
    const float* bn_gamma = (const float*)d_in[1];
    const float* bn_beta  = (const float*)d_in[2];
    const float* w_ih[3]  = {(const float*)d_in[3], (const float*)d_in[7],  (const float*)d_in[11]};
    const float* w_hh[3]  = {(const float*)d_in[4], (const float*)d_in[8],  (const float*)d_in[12]};
    const float* b_ih[3]  = {(const float*)d_in[5], (const float*)d_in[9],  (const float*)d_in[13]};
    const float* b_hh[3]  = {(const float*)d_in[6], (const float*)d_in[10], (const float*)d_in[14]};
    const float* fc_w     = (const float*)d_in[15];
    const float* fc_b     = (const float*)d_in[16];

    float* out = (float*)d_out;
    float* enc = out + NBAT * NCLS;                       // [256][64][2048] fp32

    // ---- workspace bump allocator (256B aligned) ----
    char* base = (char*)d_ws;
    size_t off = 0;
    auto alloc = [&](size_t bytes) {
        void* p = base + off;
        off += (bytes + 255) & ~(size_t)255;
        return p;
    };
    float* mean      = (float*)alloc(IN0 * 4);
    float* istd      = (float*)alloc(IN0 * 4);
    short* xn_bf     = (short*)alloc((size_t)NBAT * TT * IN0P * 2);
    short* wih0_bf   = (short*)alloc((size_t)2 * G3 * IN0P * 2);
    short* wih_bf    = (short*)alloc((size_t)2 * G3 * ENC_W * 2);
    short* whh_bf    = (short*)alloc((size_t)2 * G3 * HH * 2);
    float* h         = (float*)alloc((size_t)2 * NBAT * HH * 4);
    short* hbf       = (short*)alloc((size_t)2 * 2 * NBAT * HH * 2);  // double buffer
    short* enc_bf    = (short*)alloc((size_t)NBAT * TT * ENC_W * 2);
    size_t fixed = off;

    // pick largest Tc whose gi chunk fits in remaining ws
    int Tc = 1;
    for (int cand : {16, 8, 4, 2, 1}) {
        size_t gi_bytes = (size_t)2 * NBAT * cand * G3 * 4;
        if (fixed + gi_bytes + 1024 <= ws_size) { Tc = cand; break; }
    }
    float* gi = (float*)alloc((size_t)2 * NBAT * Tc * G3 * 4);
    int Mchunk = NBAT * Tc;

    // ---- BN ----
    bigru_bn_stats<<<IN0, 256, 0, stream>>>(x, mean, istd);
    bigru_bn_apply_bf16<<<(NBAT * TT * IN0P + 255) / 256, 256, 0, stream>>>(
        x, mean, istd, bn_gamma, bn_beta, xn_bf);

    // ---- weight conversions (layer-0 padded) ----
    bigru_cvt_wih0<<<(2 * G3 * IN0P + 255) / 256, 256, 0, stream>>>(w_ih[0], wih0_bf);

    for (int l = 0; l < 3; ++l) {
        if (l > 0) {
            int n4 = (2 * G3 * ENC_W) / 4;
            bigru_cvt4<<<(n4 + 255) / 256, 256, 0, stream>>>(w_ih[l], wih_bf, n4);
        }
        {
            int n4 = (2 * G3 * HH) / 4;
            bigru_cvt4<<<(n4 + 255) / 256, 256, 0, stream>>>(w_hh[l], whh_bf, n4);
        }
        hipMemsetAsync(h, 0, (size_t)2 * NBAT * HH * 4, stream);
        hipMemsetAsync(hbf, 0, (size_t)2 * 2 * NBAT * HH * 2, stream);

        const short* Abase = (l == 0) ? xn_bf : enc_bf;
        int ldA = (l == 0) ? IN0P : ENC_W;
        int K   = (l == 0) ? IN0P : ENC_W;
        const short* W = (l == 0) ? wih0_bf : wih_bf;
        short* enc_bf_out = (l == 2) ? nullptr : enc_bf;

        for (int t0 = 0; t0 < TT; t0 += Tc) {
            bigru_gi_gemm<<<dim3(G3 / 128, Mchunk / 128, 2), 256, 0, stream>>>(
                Abase, ldA, K, W, b_ih[l], gi, t0, Mchunk);
            for (int tt = 0; tt < Tc; ++tt) {
                int t = t0 + tt;
                const short* hin = hbf + (size_t)(t & 1) * 2 * NBAT * HH;
                short* hout      = hbf + (size_t)((t + 1) & 1) * 2 * NBAT * HH;
                bigru_step<<<dim3(HH / 64, NBAT / 64, 2), 256, 0, stream>>>(
                    hin, hout, h, whh_bf, b_hh[l], gi, tt, t, Mchunk, enc, enc_bf_out);
            }
        }
    }

    bigru_fc<<<NBAT, 256, 0, stream>>>(enc, fc_w, fc_b, out);
}